// Round 1
// baseline (941.745 us; speedup 1.0000x reference)
//
#include <hip/hip_runtime.h>
#include <cstddef>

// Problem constants (from reference)
#define BB   16
#define HHY  128
#define WWX  256
#define CC   64
#define DDp  12
#define HOUT 1024
#define WOUT 2048

// ---------------------------------------------------------------------------
// Kernel 1: cost volume. cost[b,h,w,d] = sum_c |L[b,h,w,c] - Rshift_d[b,h,w,c]|
// Rshift_d[w] = R[w-d] for w>=d else 0.
// One thread per (b,h,w); block = one (b,h) row of 256 w.
// ---------------------------------------------------------------------------
__global__ __launch_bounds__(256) void cost_volume_k(const float* __restrict__ L,
                                                     const float* __restrict__ R,
                                                     float* __restrict__ cost) {
  const int w = threadIdx.x;
  const int h = blockIdx.x;
  const int b = blockIdx.y;
  const size_t rowbase = ((size_t)(b * HHY + h)) * WWX;
  const float* lp   = L + (rowbase + w) * CC;
  const float* rrow = R + rowbase * CC;

  float acc[DDp];
#pragma unroll
  for (int d = 0; d < DDp; ++d) acc[d] = 0.f;

  for (int c = 0; c < CC; c += 4) {
    const float4 l4 = *(const float4*)(lp + c);
#pragma unroll
    for (int d = 0; d < DDp; ++d) {
      float4 r4 = make_float4(0.f, 0.f, 0.f, 0.f);
      if (w >= d) r4 = *(const float4*)(rrow + (size_t)(w - d) * CC + c);
      acc[d] += fabsf(l4.x - r4.x) + fabsf(l4.y - r4.y) +
                fabsf(l4.z - r4.z) + fabsf(l4.w - r4.w);
    }
  }

  float* cp = cost + (rowbase + w) * DDp;
#pragma unroll
  for (int d = 0; d < DDp; d += 4) {
    *(float4*)(cp + d) = make_float4(acc[d], acc[d + 1], acc[d + 2], acc[d + 3]);
  }
}

// ---------------------------------------------------------------------------
// Kernel 2..6: conv3d 3x3x3 over (H,W,D), SAME zero padding, layout [B,H,W,D,C].
// w: [3,3,3,CIN,COUT] (HWDIO). One thread per (b,h,w): all D x COUT outputs in
// registers. Weight loads are wave-uniform (scalar-cache friendly).
// ---------------------------------------------------------------------------
template <int CIN, int COUT, bool RELU>
__global__ __launch_bounds__(256) void conv3d_k(const float* __restrict__ x,
                                                const float* __restrict__ wt,
                                                const float* __restrict__ bs,
                                                float* __restrict__ y) {
  const int w = threadIdx.x;
  const int h = blockIdx.x;
  const int b = blockIdx.y;

  float acc[DDp][COUT];
  float bias[COUT];
#pragma unroll
  for (int co = 0; co < COUT; ++co) bias[co] = bs[co];
#pragma unroll
  for (int d = 0; d < DDp; ++d)
#pragma unroll
    for (int co = 0; co < COUT; ++co) acc[d][co] = bias[co];

#pragma unroll
  for (int kh = 0; kh < 3; ++kh) {
    const int hh = h + kh - 1;
    if (hh < 0 || hh >= HHY) continue;
#pragma unroll
    for (int kw = 0; kw < 3; ++kw) {
      const int ww = w + kw - 1;
      if (ww < 0 || ww >= WWX) continue;

      const float* xp = x + ((size_t)(b * HHY + hh) * WWX + ww) * DDp * CIN;
      float v[DDp * CIN];
#pragma unroll
      for (int i = 0; i < (DDp * CIN) / 4; ++i)
        ((float4*)v)[i] = ((const float4*)xp)[i];

      const float* wp = wt + (kh * 3 + kw) * 3 * CIN * COUT;
      float wr[3 * CIN * COUT];
#pragma unroll
      for (int i = 0; i < 3 * CIN * COUT; ++i) wr[i] = wp[i];

#pragma unroll
      for (int kd = 0; kd < 3; ++kd) {
#pragma unroll
        for (int d = 0; d < DDp; ++d) {
          const int dd = d + kd - 1;
          if (dd < 0 || dd >= DDp) continue;
#pragma unroll
          for (int ci = 0; ci < CIN; ++ci)
#pragma unroll
            for (int co = 0; co < COUT; ++co)
              acc[d][co] += v[dd * CIN + ci] * wr[(kd * CIN + ci) * COUT + co];
        }
      }
    }
  }

  float ov[DDp * COUT];
#pragma unroll
  for (int d = 0; d < DDp; ++d)
#pragma unroll
    for (int co = 0; co < COUT; ++co) {
      float r = acc[d][co];
      if (RELU) r = fmaxf(r, 0.f);
      ov[d * COUT + co] = r;
    }

  float* yp = y + ((size_t)(b * HHY + h) * WWX + w) * DDp * COUT;
#pragma unroll
  for (int i = 0; i < (DDp * COUT) / 4; ++i)
    ((float4*)yp)[i] = ((float4*)ov)[i];
}

// ---------------------------------------------------------------------------
// Kernel 7: softmax(-cost) over D + disparity regression -> pred[b,h,w]
// ---------------------------------------------------------------------------
__global__ __launch_bounds__(256) void softmax_regress_k(const float* __restrict__ cost,
                                                         float* __restrict__ pred,
                                                         int n) {
  const int i = blockIdx.x * 256 + threadIdx.x;
  if (i >= n) return;
  const float* cp = cost + (size_t)i * DDp;
  float c[DDp];
#pragma unroll
  for (int j = 0; j < DDp / 4; ++j) ((float4*)c)[j] = ((const float4*)cp)[j];
  float mn = c[0];
#pragma unroll
  for (int d = 1; d < DDp; ++d) mn = fminf(mn, c[d]);
  float s = 0.f, sw = 0.f;
#pragma unroll
  for (int d = 0; d < DDp; ++d) {
    const float e = __expf(mn - c[d]);  // softmax(-cost): max(-c) = -min(c)
    s += e;
    sw += e * (float)d;
  }
  pred[i] = sw / s;
}

// ---------------------------------------------------------------------------
// Kernel 8: 8x bilinear upsample (jax.image.resize half-pixel convention,
// edge weights normalized == coordinate clamp for the linear kernel).
// ---------------------------------------------------------------------------
__global__ __launch_bounds__(256) void resize_k(const float* __restrict__ pred,
                                                float* __restrict__ out) {
  const int idx = blockIdx.x * 256 + threadIdx.x;  // b*HOUT*WOUT + y*WOUT + x
  const int x = idx & (WOUT - 1);
  const int y = (idx >> 11) & (HOUT - 1);
  const int b = idx >> 21;

  float fy = (y + 0.5f) * 0.125f - 0.5f;
  float fx = (x + 0.5f) * 0.125f - 0.5f;
  fy = fminf(fmaxf(fy, 0.f), (float)(HHY - 1));
  fx = fminf(fmaxf(fx, 0.f), (float)(WWX - 1));
  const int y0 = (int)fy;
  const int x0 = (int)fx;
  const int y1 = min(y0 + 1, HHY - 1);
  const int x1 = min(x0 + 1, WWX - 1);
  const float wy = fy - (float)y0;
  const float wx = fx - (float)x0;

  const float* pb = pred + (size_t)b * HHY * WWX;
  const float p00 = pb[y0 * WWX + x0];
  const float p01 = pb[y0 * WWX + x1];
  const float p10 = pb[y1 * WWX + x0];
  const float p11 = pb[y1 * WWX + x1];

  out[idx] = (p00 * (1.f - wx) + p01 * wx) * (1.f - wy) +
             (p10 * (1.f - wx) + p11 * wx) * wy;
}

// ---------------------------------------------------------------------------
extern "C" void kernel_launch(void* const* d_in, const int* in_sizes, int n_in,
                              void* d_out, int out_size, void* d_ws, size_t ws_size,
                              hipStream_t stream) {
  const float* feat_l = (const float*)d_in[0];
  const float* feat_r = (const float*)d_in[1];
  const float* w0 = (const float*)d_in[2];
  const float* b0 = (const float*)d_in[3];
  const float* w1 = (const float*)d_in[4];
  const float* b1 = (const float*)d_in[5];
  const float* w2 = (const float*)d_in[6];
  const float* b2 = (const float*)d_in[7];
  const float* w3 = (const float*)d_in[8];
  const float* b3 = (const float*)d_in[9];
  const float* wf = (const float*)d_in[10];
  const float* bf = (const float*)d_in[11];
  float* out = (float*)d_out;

  // Workspace layout: two ping-pong buffers of [B,H,W,D,4] f32 (100.7 MB each).
  // cost volume (25 MB, [B,H,W,D]) lives at the start of bufA; final 1-channel
  // cost lives at the start of bufB; pred (2 MB) reuses bufA.
  char* ws = (char*)d_ws;
  const size_t buf_bytes = (size_t)BB * HHY * WWX * DDp * 4 * sizeof(float);
  float* bufA = (float*)ws;
  float* bufB = (float*)(ws + buf_bytes);

  dim3 grid(HHY, BB), blk(256);
  cost_volume_k<<<grid, blk, 0, stream>>>(feat_l, feat_r, bufA);
  conv3d_k<1, 4, true><<<grid, blk, 0, stream>>>(bufA, w0, b0, bufB);
  conv3d_k<4, 4, true><<<grid, blk, 0, stream>>>(bufB, w1, b1, bufA);
  conv3d_k<4, 4, true><<<grid, blk, 0, stream>>>(bufA, w2, b2, bufB);
  conv3d_k<4, 4, true><<<grid, blk, 0, stream>>>(bufB, w3, b3, bufA);
  conv3d_k<4, 1, false><<<grid, blk, 0, stream>>>(bufA, wf, bf, bufB);

  const int nbhw = BB * HHY * WWX;
  softmax_regress_k<<<dim3((nbhw + 255) / 256), blk, 0, stream>>>(bufB, bufA, nbhw);

  const int nout = BB * HOUT * WOUT;
  resize_k<<<dim3((nout + 255) / 256), blk, 0, stream>>>(bufA, out);
}

// Round 2
// 466.986 us; speedup vs baseline: 2.0166x; 2.0166x over previous
//
#include <hip/hip_runtime.h>
#include <cstddef>

// Problem constants (from reference)
#define BB   16
#define HHY  128
#define WWX  256
#define CC   64
#define DDp  12
#define HOUT 1024
#define WOUT 2048

// ---------------------------------------------------------------------------
// Kernel 1: cost volume. cost[b,h,w,d] = sum_c |L[b,h,w,c] - R[b,h,w-d,c]|
// (R shifted with zero pad: w<d contributes sum_c |L|).
// Block = one (b,h) row (256 threads, thread = w). L and R rows are staged in
// LDS in 16-channel chunks with coalesced float4 global loads; LDS rows are
// padded to stride 20 floats so ds_read_b128 bank coverage is uniform.
// ---------------------------------------------------------------------------
#define CCH 16  // channel chunk
#define LST 20  // LDS stride in floats per w (pad 16 -> 20)

__global__ __launch_bounds__(256) void cost_volume_k(const float* __restrict__ L,
                                                     const float* __restrict__ R,
                                                     float* __restrict__ cost) {
  __shared__ float lsL[WWX * LST];
  __shared__ float lsR[WWX * LST];
  const int t = threadIdx.x;
  const int h = blockIdx.x;
  const int b = blockIdx.y;
  const size_t rowbase = ((size_t)(b * HHY + h)) * WWX;
  const float* Lrow = L + rowbase * CC;
  const float* Rrow = R + rowbase * CC;

  float acc[DDp];
#pragma unroll
  for (int d = 0; d < DDp; ++d) acc[d] = 0.f;

  for (int c0 = 0; c0 < CC; c0 += CCH) {
    __syncthreads();  // protect LDS from previous iteration's readers
    // Stage this channel chunk of both rows, coalesced.
#pragma unroll
    for (int j = 0; j < 4; ++j) {
      const int i = t + 256 * j;   // float4 id in [0,1024)
      const int w = i >> 2;
      const int r4 = (i & 3) << 2; // float offset within chunk
      const size_t g = (size_t)w * CC + c0 + r4;
      *(float4*)(&lsL[w * LST + r4]) = *(const float4*)(Lrow + g);
      *(float4*)(&lsR[w * LST + r4]) = *(const float4*)(Rrow + g);
    }
    __syncthreads();

    const int w = t;
    float l[CCH];
#pragma unroll
    for (int k = 0; k < CCH / 4; ++k)
      ((float4*)l)[k] = *(const float4*)(&lsL[w * LST + 4 * k]);

    // sum |l| once for the zero-pad (w < d) case
    float sl = 0.f;
#pragma unroll
    for (int k = 0; k < CCH; ++k) sl += fabsf(l[k]);

#pragma unroll
    for (int d = 0; d < DDp; ++d) {
      if (w >= d) {
        const float* rp = &lsR[(w - d) * LST];
        float a = 0.f;
#pragma unroll
        for (int k = 0; k < CCH / 4; ++k) {
          const float4 r4 = *(const float4*)(rp + 4 * k);
          a += fabsf(l[4 * k + 0] - r4.x) + fabsf(l[4 * k + 1] - r4.y) +
               fabsf(l[4 * k + 2] - r4.z) + fabsf(l[4 * k + 3] - r4.w);
        }
        acc[d] += a;
      } else {
        acc[d] += sl;
      }
    }
  }

  float* cp = cost + (rowbase + t) * DDp;
#pragma unroll
  for (int d = 0; d < DDp; d += 4)
    *(float4*)(cp + d) = make_float4(acc[d], acc[d + 1], acc[d + 2], acc[d + 3]);
}

// ---------------------------------------------------------------------------
// Conv3d 3x3x3 over (H,W,D), SAME zero pad, layout [B,H,W,D,CIN].
// Block = one (b,h) output row. For each kh tap the input row h+kh-1 is staged
// into LDS (padded stride) with coalesced loads; each thread then computes all
// D x COUT outputs for its w. Weight loads are wave-uniform (scalar path).
// FUSE_SM: final conv variant that also does softmax(-cost)+regression and
// writes pred[b,h,w] (1 float).
// ---------------------------------------------------------------------------
template <int CIN, int COUT, bool RELU, bool FUSE_SM>
__global__ __launch_bounds__(256) void conv3d_k(const float* __restrict__ x,
                                                const float* __restrict__ wt,
                                                const float* __restrict__ bs,
                                                float* __restrict__ y) {
  constexpr int DC = DDp * CIN;             // 12 or 48
  constexpr int S = DC + (CIN == 1 ? 8 : 4);  // 20 or 52 (bank spread)
  __shared__ float ls[WWX * S];

  const int w = threadIdx.x;
  const int h = blockIdx.x;
  const int b = blockIdx.y;

  float acc[DDp][COUT];
#pragma unroll
  for (int d = 0; d < DDp; ++d)
#pragma unroll
    for (int co = 0; co < COUT; ++co) acc[d][co] = bs[co];

#pragma unroll
  for (int kh = 0; kh < 3; ++kh) {
    const int hh = h + kh - 1;
    if (hh < 0 || hh >= HHY) continue;  // block-uniform -> safe with syncs

    __syncthreads();
    const float* xr = x + ((size_t)(b * HHY + hh) * WWX) * DC;
    constexpr int N4 = WWX * DC / 4;  // 768 or 3072 float4s
#pragma unroll
    for (int j = 0; j < N4 / 256; ++j) {
      const int g4 = w + 256 * j;
      const int f = g4 * 4;
      const int ww = f / DC;
      const int r = f - ww * DC;
      *(float4*)(&ls[ww * S + r]) = *(const float4*)(xr + f);
    }
    __syncthreads();

#pragma unroll
    for (int kw = 0; kw < 3; ++kw) {
      const int ww = w + kw - 1;
      if (ww < 0 || ww >= WWX) continue;  // divergent only at row edges

      float v[DC];
#pragma unroll
      for (int k = 0; k < DC / 4; ++k)
        ((float4*)v)[k] = *(const float4*)(&ls[ww * S + 4 * k]);

      const float* wp = wt + (size_t)(kh * 3 + kw) * 3 * CIN * COUT;
      float wr[3 * CIN * COUT];
#pragma unroll
      for (int i = 0; i < 3 * CIN * COUT; ++i) wr[i] = wp[i];

#pragma unroll
      for (int kd = 0; kd < 3; ++kd) {
#pragma unroll
        for (int d = 0; d < DDp; ++d) {
          const int dd = d + kd - 1;
          if (dd < 0 || dd >= DDp) continue;
#pragma unroll
          for (int ci = 0; ci < CIN; ++ci)
#pragma unroll
            for (int co = 0; co < COUT; ++co)
              acc[d][co] += v[dd * CIN + ci] * wr[(kd * CIN + ci) * COUT + co];
        }
      }
    }
  }

  if (FUSE_SM) {
    // softmax(-cost) over d + disparity regression
    float mn = acc[0][0];
#pragma unroll
    for (int d = 1; d < DDp; ++d) mn = fminf(mn, acc[d][0]);
    float s = 0.f, sw = 0.f;
#pragma unroll
    for (int d = 0; d < DDp; ++d) {
      const float e = __expf(mn - acc[d][0]);
      s += e;
      sw += e * (float)d;
    }
    y[(size_t)(b * HHY + h) * WWX + w] = sw / s;
  } else {
    float ov[DDp * COUT];
#pragma unroll
    for (int d = 0; d < DDp; ++d)
#pragma unroll
      for (int co = 0; co < COUT; ++co) {
        float r = acc[d][co];
        if (RELU) r = fmaxf(r, 0.f);
        ov[d * COUT + co] = r;
      }
    float* yp = y + ((size_t)(b * HHY + h) * WWX + w) * DC * COUT / CIN;
#pragma unroll
    for (int i = 0; i < (DDp * COUT) / 4; ++i)
      ((float4*)yp)[i] = ((float4*)ov)[i];
  }
}

// ---------------------------------------------------------------------------
// 8x bilinear upsample (jax.image.resize half-pixel convention; edge weight
// renormalization == coordinate clamp for the triangle kernel).
// ---------------------------------------------------------------------------
__global__ __launch_bounds__(256) void resize_k(const float* __restrict__ pred,
                                                float* __restrict__ out) {
  const int idx = blockIdx.x * 256 + threadIdx.x;
  const int x = idx & (WOUT - 1);
  const int y = (idx >> 11) & (HOUT - 1);
  const int b = idx >> 21;

  float fy = (y + 0.5f) * 0.125f - 0.5f;
  float fx = (x + 0.5f) * 0.125f - 0.5f;
  fy = fminf(fmaxf(fy, 0.f), (float)(HHY - 1));
  fx = fminf(fmaxf(fx, 0.f), (float)(WWX - 1));
  const int y0 = (int)fy;
  const int x0 = (int)fx;
  const int y1 = min(y0 + 1, HHY - 1);
  const int x1 = min(x0 + 1, WWX - 1);
  const float wy = fy - (float)y0;
  const float wx = fx - (float)x0;

  const float* pb = pred + (size_t)b * HHY * WWX;
  const float p00 = pb[y0 * WWX + x0];
  const float p01 = pb[y0 * WWX + x1];
  const float p10 = pb[y1 * WWX + x0];
  const float p11 = pb[y1 * WWX + x1];

  out[idx] = (p00 * (1.f - wx) + p01 * wx) * (1.f - wy) +
             (p10 * (1.f - wx) + p11 * wx) * wy;
}

// ---------------------------------------------------------------------------
extern "C" void kernel_launch(void* const* d_in, const int* in_sizes, int n_in,
                              void* d_out, int out_size, void* d_ws, size_t ws_size,
                              hipStream_t stream) {
  const float* feat_l = (const float*)d_in[0];
  const float* feat_r = (const float*)d_in[1];
  const float* w0 = (const float*)d_in[2];
  const float* b0 = (const float*)d_in[3];
  const float* w1 = (const float*)d_in[4];
  const float* b1 = (const float*)d_in[5];
  const float* w2 = (const float*)d_in[6];
  const float* b2 = (const float*)d_in[7];
  const float* w3 = (const float*)d_in[8];
  const float* b3 = (const float*)d_in[9];
  const float* wf = (const float*)d_in[10];
  const float* bf = (const float*)d_in[11];
  float* out = (float*)d_out;

  // ws: two ping-pong buffers of [B,H,W,D,4] f32 (100.7 MB each).
  // cost volume ([B,H,W,D], 25 MB) lives at start of bufA; pred ([B,H,W],
  // 2 MB) lives at start of bufB after the final fused conv.
  char* ws = (char*)d_ws;
  const size_t buf_bytes = (size_t)BB * HHY * WWX * DDp * 4 * sizeof(float);
  float* bufA = (float*)ws;
  float* bufB = (float*)(ws + buf_bytes);

  dim3 grid(HHY, BB), blk(256);
  cost_volume_k<<<grid, blk, 0, stream>>>(feat_l, feat_r, bufA);
  conv3d_k<1, 4, true, false><<<grid, blk, 0, stream>>>(bufA, w0, b0, bufB);
  conv3d_k<4, 4, true, false><<<grid, blk, 0, stream>>>(bufB, w1, b1, bufA);
  conv3d_k<4, 4, true, false><<<grid, blk, 0, stream>>>(bufA, w2, b2, bufB);
  conv3d_k<4, 4, true, false><<<grid, blk, 0, stream>>>(bufB, w3, b3, bufA);
  conv3d_k<4, 1, false, true><<<grid, blk, 0, stream>>>(bufA, wf, bf, bufB);

  const int nout = BB * HOUT * WOUT;
  resize_k<<<dim3((nout + 255) / 256), blk, 0, stream>>>(bufB, out);
}